// Round 5
// baseline (263.140 us; speedup 1.0000x reference)
//
#include <hip/hip_runtime.h>
#include <hip/hip_bf16.h>

// QuantizedLinear: out[8192,4096] = x[8192,4096] @ W^T + bias
//   W[n,k] = codebooks[codes[n, k/8]][k%8] * scales[n]  (NCB=1; scale folded into epilogue)
// Pipeline: cvt x->bf16, dequant W->bf16 [N][K], then 256x256 MFMA GEMM.
// Round-5 schedule: ds_reads interleaved INSIDE the MFMA clusters (between the
// two 8-MFMA halves, reusing af regs whose consumers already issued), so LDS
// service runs concurrently with MFMA. Window-head LGKMs wait on reads issued
// >=1 MFMA-batch earlier. Same vmcnt/barrier/stage invariants as round 3.
#define M_DIM 8192
#define N_DIM 4096
#define K_DIM 4096
#define NOG 4096
#define NIG 512

typedef __bf16 bf16x8 __attribute__((ext_vector_type(8)));
typedef float f32x4 __attribute__((ext_vector_type(4)));
typedef short short8 __attribute__((ext_vector_type(8)));

typedef const __attribute__((address_space(1))) void* as1_cvoid_p;
typedef __attribute__((address_space(3))) void* as3_void_p;

__device__ __forceinline__ unsigned short f2bf(float f) {
  union { float f; unsigned u; } c; c.f = f;
  unsigned u = c.u;
  return (unsigned short)((u + 0x7fffu + ((u >> 16) & 1u)) >> 16);
}

// ---- Kernel 1: x f32 -> bf16
__global__ __launch_bounds__(256) void cvt_x_kernel(const float* __restrict__ x,
                                                    unsigned short* __restrict__ xb,
                                                    int n8) {
  int i = blockIdx.x * blockDim.x + threadIdx.x;
  int stride = gridDim.x * blockDim.x;
  for (; i < n8; i += stride) {
    const float4* p = (const float4*)(x) + (size_t)i * 2;
    float4 a = p[0], b = p[1];
    short8 o;
    o[0] = (short)f2bf(a.x); o[1] = (short)f2bf(a.y);
    o[2] = (short)f2bf(a.z); o[3] = (short)f2bf(a.w);
    o[4] = (short)f2bf(b.x); o[5] = (short)f2bf(b.y);
    o[6] = (short)f2bf(b.z); o[7] = (short)f2bf(b.w);
    ((short8*)xb)[i] = o;
  }
}

// ---- Kernel 2: gather-dequant -> bf16 W [N][K]
__global__ __launch_bounds__(256) void dequant_kernel(const int* __restrict__ codes,
                                                      const float* __restrict__ cb,
                                                      unsigned short* __restrict__ wb) {
  int idx = blockIdx.x * blockDim.x + threadIdx.x;
  int code = codes[idx];
  const float4* p = (const float4*)(cb + (size_t)code * 8);
  float4 a = p[0], b = p[1];
  short8 o;
  o[0] = (short)f2bf(a.x); o[1] = (short)f2bf(a.y);
  o[2] = (short)f2bf(a.z); o[3] = (short)f2bf(a.w);
  o[4] = (short)f2bf(b.x); o[5] = (short)f2bf(b.y);
  o[6] = (short)f2bf(b.z); o[7] = (short)f2bf(b.w);
  ((short8*)wb)[idx] = o;
}

// ---- Kernel 3: 256x256 GEMM, BK=64, 8 waves (2Mx4N), 128 KiB LDS (2 slots),
// st_16x32 swizzle. Stages: W0:AH(t+1)->s^1  W1:AL(t+2)->s  W2:BL(t+2)->s  W3:BH(t+2)->s.
// Read issue points: W0-head: bf1<-bH(t). W1 mid: af<-aHq1/aHq2(t).
// W3 mid: af<-aLq1(t+1)+bf0<-bL(t+1), af<-aLq2(t+1).
// Waits: LGKM(4)@W0, 0@W1, 4/0@W2; VMC(8)@W0-end, VMC(6)@W2-end; barriers end-W0/W1/W2.

#define BAR() __builtin_amdgcn_s_barrier()
#define SB() __builtin_amdgcn_sched_barrier(0)
#define PRIO1() __builtin_amdgcn_s_setprio(1)
#define PRIO0() __builtin_amdgcn_s_setprio(0)
#define LGKM(N_) asm volatile("s_waitcnt lgkmcnt(" #N_ ")" ::: "memory")
#define VMC(N_) asm volatile("s_waitcnt vmcnt(" #N_ ")" ::: "memory")

#define STAGE_A(slot_, h_, kt_) do { \
  _Pragma("unroll") for (int i_ = 0; i_ < 2; ++i_) { \
    const unsigned short* src_ = Ag + (size_t)(sa_roff[i_] + (h_) * 64) * 4096 + (unsigned)((kt_) + sa_koff[i_]); \
    __builtin_amdgcn_global_load_lds((as1_cvoid_p)src_, \
      (as3_void_p)(smem + (slot_) * 32768 + sa_lds[i_] + (h_) * 4096), 16, 0, 0); \
  } } while (0)

#define STAGE_B(slot_, h_, kt_) do { \
  _Pragma("unroll") for (int i_ = 0; i_ < 2; ++i_) { \
    const unsigned short* src_ = Bg + (size_t)(sb_roff[i_] + (h_) * 32) * 4096 + (unsigned)((kt_) + sb_koff[i_]); \
    __builtin_amdgcn_global_load_lds((as1_cvoid_p)src_, \
      (as3_void_p)(smem + 65536 + (slot_) * 32768 + sb_lds[i_] + (h_) * 2048), 16, 0, 0); \
  } } while (0)

// quarter A-fragment read: q_=0 -> af[0..1], q_=1 -> af[2..3]; ma_ = A half (0/1)
#define LDA_Q(q_, ma_, slot_) \
  _Pragma("unroll") for (int j_ = 0; j_ < 2; ++j_) \
  _Pragma("unroll") for (int kk_ = 0; kk_ < 2; ++kk_) \
    af[(q_) * 2 + j_][kk_] = *(const bf16x8*)(smem + (slot_) * 32768 + aRd + ((ma_) * 4 + (q_) * 2 + j_) * 1024 + kk_ * 16384);

#define LDB(n0_, dst_, slot_) \
  _Pragma("unroll") for (int n_ = 0; n_ < 2; ++n_) \
  _Pragma("unroll") for (int kk_ = 0; kk_ < 2; ++kk_) \
    dst_[n_][kk_] = *(const bf16x8*)(smem + (slot_) * 32768 + bRd + ((n0_) + n_) * 1024 + kk_ * 16384);

// 8 MFMAs: acc rows base_+q_*2..+1, cols nb_..nb_+1
#define MM_Q(base_, q_, nb_, bfr_) \
  _Pragma("unroll") for (int j_ = 0; j_ < 2; ++j_) \
  _Pragma("unroll") for (int n_ = 0; n_ < 2; ++n_) \
  _Pragma("unroll") for (int kk_ = 0; kk_ < 2; ++kk_) \
    acc[(base_) + (q_) * 2 + j_][(nb_) + n_] = __builtin_amdgcn_mfma_f32_16x16x32_bf16( \
        af[(q_) * 2 + j_][kk_], bfr_[n_][kk_], acc[(base_) + (q_) * 2 + j_][(nb_) + n_], 0, 0, 0);

// MODE: 2=steady, 1=g=62 (stage AH only; VMC 8/2), 0=g=63 (VMC(0)@W0; no next-tile reads)
#define GROUP(SLOT_, MODE_, KT_) do { \
  /* W0: head read bf1<-bH(t); LGKM(4) [aLq1,bL,aLq2]; 16 MFMA aL x bL; stage AH(t+1) */ \
  LDB(2, bf1, SLOT_); SB(); \
  LGKM(4); SB(); \
  PRIO1(); MM_Q(0, 0, 0, bf0); MM_Q(0, 1, 0, bf0); PRIO0(); SB(); \
  if ((MODE_) >= 1) STAGE_A((SLOT_) ^ 1, 1, (KT_) + 64); \
  if ((MODE_) >= 1) { VMC(8); } else { VMC(0); } \
  BAR(); \
  /* W1: LGKM(0) [bH]; MM8 aL01 x bH; read af01<-aHq1; MM8 aL23 x bH; read af23<-aHq2; stage AL(t+2) */ \
  LGKM(0); SB(); \
  PRIO1(); MM_Q(0, 0, 2, bf1); PRIO0(); SB(); \
  LDA_Q(0, 1, SLOT_); SB(); \
  PRIO1(); MM_Q(0, 1, 2, bf1); PRIO0(); SB(); \
  LDA_Q(1, 1, SLOT_); SB(); \
  if ((MODE_) == 2) STAGE_A(SLOT_, 0, (KT_) + 128); \
  BAR(); \
  /* W2: LGKM(4) [aHq1]; MM8 aH01 x bL; LGKM(0) [aHq2]; MM8 aH23 x bL; stage BL(t+2) */ \
  LGKM(4); SB(); \
  PRIO1(); MM_Q(4, 0, 0, bf0); PRIO0(); SB(); \
  LGKM(0); SB(); \
  PRIO1(); MM_Q(4, 1, 0, bf0); PRIO0(); SB(); \
  if ((MODE_) == 2) STAGE_B(SLOT_, 0, (KT_) + 128); \
  if ((MODE_) == 2) { VMC(6); } else if ((MODE_) == 1) { VMC(2); } \
  BAR(); \
  /* W3: MM8 aH01 x bH; read af01<-aLq1(t+1)+bf0<-bL(t+1); MM8 aH23 x bH; read af23<-aLq2(t+1); stage BH(t+2); no BAR */ \
  PRIO1(); MM_Q(4, 0, 2, bf1); PRIO0(); SB(); \
  if ((MODE_) >= 1) { LDA_Q(0, 0, (SLOT_) ^ 1); LDB(0, bf0, (SLOT_) ^ 1); } \
  SB(); \
  PRIO1(); MM_Q(4, 1, 2, bf1); PRIO0(); SB(); \
  if ((MODE_) >= 1) { LDA_Q(1, 0, (SLOT_) ^ 1); } \
  SB(); \
  if ((MODE_) == 2) STAGE_B(SLOT_, 1, (KT_) + 128); \
} while (0)

__global__ __launch_bounds__(512) void gemm8_kernel(
    const unsigned short* __restrict__ A,   // bf16 [M][K]
    const unsigned short* __restrict__ B,   // bf16 [N][K]
    const float* __restrict__ scales,
    const float* __restrict__ bias,
    float* __restrict__ C) {
  extern __shared__ char smem[];  // 131072 B

  // grid 512 = 32 bm x 16 bn; bijective XCD swizzle (512 % 8 == 0)
  const int bid = blockIdx.x;
  const int swz = (bid & 7) * 64 + (bid >> 3);
  const int bm = swz >> 4;
  const int bn = swz & 15;

  const int tid = threadIdx.x;
  const int w = tid >> 6;
  const int l = tid & 63;
  const int wr = w >> 2;    // 0..1
  const int wcol = w & 3;   // 0..3

  // ---- staging constants (linear LDS dest, inverse-swizzled global source)
  const int llog = l ^ (((l >> 5) & 1) << 1);
  int sa_roff[2], sa_koff[2], sa_lds[2];
  int sb_roff[2], sb_koff[2], sb_lds[2];
#pragma unroll
  for (int i = 0; i < 2; ++i) {
    int u = w * 2 + i;
    int panel = u >> 3;
    int rbA = (u >> 2) & 1, chA = u & 3;
    sa_roff[i] = rbA * 128 + chA * 16 + (llog >> 2);
    sa_koff[i] = panel * 32 + (llog & 3) * 8;
    sa_lds[i] = panel * 16384 + rbA * 8192 + chA * 1024;
    int bb = (u >> 1) & 3, hk = u & 1;
    sb_roff[i] = bb * 64 + hk * 16 + (llog >> 2);
    sb_koff[i] = panel * 32 + (llog & 3) * 8;
    sb_lds[i] = panel * 16384 + bb * 4096 + hk * 1024;
  }

  const unsigned short* Ag = A + (size_t)bm * 256 * 4096;
  const unsigned short* Bg = B + (size_t)bn * 256 * 4096;

  // ---- fragment read base addresses (swizzled)
  const int xr = ((l >> 4) * 16) ^ (((l >> 3) & 1) << 5);
  const int aRd = (wr * 128 + (l & 15)) * 64 + xr;
  const int bRd = 65536 + (wcol * 64 + (l & 15)) * 64 + xr;

  f32x4 acc[8][4];
#pragma unroll
  for (int m = 0; m < 8; ++m)
#pragma unroll
    for (int n = 0; n < 4; ++n) acc[m][n] = (f32x4){0.f, 0.f, 0.f, 0.f};

  bf16x8 af[4][2], bf0[2][2], bf1[2][2];

  // ---- prologue: stage AL0,BL0,BH0 | AH0 | AL1,BL1,BH1; drain first 3; prime reads
  STAGE_A(0, 0, 0); STAGE_B(0, 0, 0); STAGE_B(0, 1, 0);
  STAGE_A(0, 1, 0);
  STAGE_A(1, 0, 64); STAGE_B(1, 0, 64); STAGE_B(1, 1, 64);
  VMC(8);   // 14 outstanding -> keep 8 newest {AH0, AL1, BL1, BH1}
  BAR();
  // prime the steady-state read queue: aLq1(0), bL(0), aLq2(0)
  LDA_Q(0, 0, 0); SB(); LDB(0, bf0, 0); SB(); LDA_Q(1, 0, 0); SB();

  // ---- main loop: 64 K-tiles; groups 0..61 steady, 62 penult, 63 last
  int kt = 0;
  for (int j = 0; j < 31; ++j) {
    GROUP(0, 2, kt);
    GROUP(1, 2, kt + 64);
    kt += 128;
  }
  GROUP(0, 1, kt);        // g=62: stages AH(63) only
  GROUP(1, 0, kt + 64);   // g=63

  // ---- epilogue: scale + bias, fp32 store
  const int row0 = bm * 256 + wr * 128 + ((l >> 4) << 2);
  const int col0 = bn * 256 + wcol * 64 + (l & 15);
#pragma unroll
  for (int n = 0; n < 4; ++n) {
    const int col = col0 + n * 16;
    const float s = scales[col];
    const float bv = bias[col];
#pragma unroll
    for (int m = 0; m < 8; ++m) {
      f32x4 v = acc[m][n];
      const int r = row0 + m * 16;
#pragma unroll
      for (int j = 0; j < 4; ++j)
        C[(size_t)(r + j) * 4096 + col] = v[j] * s + bv;
    }
  }
}

extern "C" void kernel_launch(void* const* d_in, const int* in_sizes, int n_in,
                              void* d_out, int out_size, void* d_ws, size_t ws_size,
                              hipStream_t stream) {
  const float* x = (const float*)d_in[0];
  const int* codes = (const int*)d_in[1];
  const float* cb = (const float*)d_in[2];
  const float* scales = (const float*)d_in[3];
  const float* bias = (const float*)d_in[4];
  float* out = (float*)d_out;

  unsigned short* xb = (unsigned short*)d_ws;
  unsigned short* wb = (unsigned short*)((char*)d_ws + (size_t)M_DIM * K_DIM * 2);

  hipFuncSetAttribute((const void*)gemm8_kernel,
                      hipFuncAttributeMaxDynamicSharedMemorySize, 131072);

  cvt_x_kernel<<<4096, 256, 0, stream>>>(x, xb, (M_DIM * K_DIM) / 8);
  dequant_kernel<<<(NOG * NIG) / 256, 256, 0, stream>>>(codes, cb, wb);
  gemm8_kernel<<<dim3((M_DIM / 256) * (N_DIM / 256)), 512, 131072, stream>>>(
      xb, wb, scales, bias, out);
}